// Round 4
// baseline (133.913 us; speedup 1.0000x reference)
//
#include <hip/hip_runtime.h>
#include <math.h>

#define Lc 13
#define Hc 1024
#define Bc 32
#define Sc 2048
#define BSc (Bc*Sc)
#define CHUNK 128
#define NCHUNK 16
#define NBLK (Bc*NCHUNK)   // 512 chunk blocks

#define ROWS 64        // rows per block (k_logits)
#define PW   32        // panel width in h
#define NP   (Hc/PW)   // 32 panels
#define NBUF 4
#define THREADS 512    // 8 waves

#define INV_LN2 1.44269504088896340736f
#define LN2f    0.69314718055994530942f

#if __has_builtin(__builtin_amdgcn_exp2f)
#define EXP2F(x) __builtin_amdgcn_exp2f(x)
#else
#define EXP2F(x) exp2f(x)
#endif
#if __has_builtin(__builtin_amdgcn_logf)
#define LOG2F(x) __builtin_amdgcn_logf(x)
#else
#define LOG2F(x) log2f(x)
#endif

// ---------------------------------------------------------------------------
// Kernel A: logits = hs @ W^T + b.
// 512 thr = 8 waves, 64 rows/block, 32 panels of 32 h, NBUF=4 ring (32 KB),
// prefetch depth 3 with COUNTED vmcnt + raw s_barrier (T3/T4): in-flight
// loads never drain to 0 in the main loop. vmcnt retires in order, and the
// 2 youngest VMEM ops at the wait are always the 2 newest stage loads, so
// vmcnt(2) == "panel p landed" independent of any other memory traffic.
// W reads wave-uniform (s_load, lgkmcnt only). 4 blocks/CU -> all 1024
// blocks resident simultaneously (no tail).
// ---------------------------------------------------------------------------
__global__ __launch_bounds__(THREADS, 8)
void k_logits(const float* __restrict__ A, const float* __restrict__ W,
              const float* __restrict__ bias, float* __restrict__ out) {
  __shared__ float buf[NBUF][ROWS * PW];   // 4 x 8 KB = 32 KB
  const int tid = threadIdx.x;
  const int ln  = tid & 63;
  const int wu  = __builtin_amdgcn_readfirstlane(tid >> 6);
  const int rowBase = blockIdx.x * ROWS;

  float acc[Lc];
#pragma unroll
  for (int l = 0; l < Lc; ++l) acc[l] = 0.f;

  // stage panel p: 64 rows x 32 floats = 8 KB = 8 loads of (64 lanes x 16B);
  // wave wu issues load wu. LDS dest linear; source inverse-swizzled (G21):
  // slot c of row stores h = (c ^ (row&7))*4.
  auto stage = [&](int p) {
    int slot = wu * 64 + ln;          // 16B slots, 8 per row
    int row  = slot >> 3;
    int c    = slot & 7;
    int h    = (c ^ (row & 7)) << 2;
    const float* gp = A + (size_t)(rowBase + row) * Hc + (size_t)p * PW + h;
    float* lp = &buf[p & (NBUF - 1)][wu * 256];   // wave-uniform base
    __builtin_amdgcn_global_load_lds(
        (const __attribute__((address_space(1))) void*)gp,
        (__attribute__((address_space(3))) void*)lp, 16, 0, 0);
  };

  // compute panel p: lane = row; wave's h-window f = wu*4 (wave-uniform ->
  // W via s_load). Swizzled ds_read_b128.
  auto compute = [&](int p) {
    const float* bp = &buf[p & (NBUF - 1)][0];
    float4 a = *(const float4*)&bp[ln * PW + ((wu ^ (ln & 7)) << 2)];
    const float* Wp = W + (size_t)p * PW + (wu << 2);
#pragma unroll
    for (int l = 0; l < Lc; ++l) {
      const float4 wv = *(const float4*)(Wp + (size_t)l * Hc);
      acc[l] += a.x * wv.x + a.y * wv.y + a.z * wv.z + a.w * wv.w;
    }
  };

  stage(0); stage(1); stage(2);
  for (int p = 0; p < NP; ++p) {
    if (p < NP - 2)      asm volatile("s_waitcnt vmcnt(2)" ::: "memory");
    else if (p == NP - 2) asm volatile("s_waitcnt vmcnt(1)" ::: "memory");
    else                  asm volatile("s_waitcnt vmcnt(0)" ::: "memory");
    __builtin_amdgcn_s_barrier();
    if (p + 3 < NP) stage(p + 3);
    compute(p);
  }

  // reduce 8 per-wave partials through LDS (flat reuse of buf: 26.6 KB < 32)
  __syncthreads();
  float* part = &buf[0][0];
#pragma unroll
  for (int l = 0; l < Lc; ++l) part[(wu * 64 + ln) * Lc + l] = acc[l];
  __syncthreads();
  for (int o = tid; o < ROWS * Lc; o += THREADS) {
    int l = o % Lc;
    float s = bias[l];
#pragma unroll
    for (int ww = 0; ww < 8; ++ww) s += part[ww * (64 * Lc) + o];
    out[(size_t)rowBase * Lc + o] = s;
  }
}

// ---------------------------------------------------------------------------
// Kernel B: per (batch, chunk) 13x13 transfer matrix, LINEAR domain
// (13 shfl + 13 fma + 1 exp2 per step; exponent-extract renorm every 8).
// Wave 0 also computes the chunk's numerator partial. Block 0 zeroes out0.
// ---------------------------------------------------------------------------
__global__ void k_chunks(const float* __restrict__ logits, const int* __restrict__ mask,
                         const int* __restrict__ labels, const float* __restrict__ T,
                         float* __restrict__ Mout, float* __restrict__ numpart,
                         float* __restrict__ cntpart, float* __restrict__ out0) {
  const int bp = blockIdx.x;
  const int b  = bp >> 4;       // NCHUNK == 16
  const int p  = bp & 15;
  const int tid = threadIdx.x;
  if (bp == 0 && tid == 0) out0[0] = 0.f;   // zero loss accumulator for k_final
  const int g = tid >> 4;
  const int k = tid & 15;
  const int kk = (k < 13) ? k : 0;
  const int gg = (g < 13) ? g : 0;
  const bool active = (g < 13) && (k < 13);
  const size_t lbase = (size_t)b * Sc;
  const int t0 = 1 + p * CHUNK;
  const int t1 = min(t0 + CHUNK, Sc);

  float U[13];   // column kk of exp(T)
#pragma unroll
  for (int j = 0; j < 13; ++j) U[j] = EXP2F(T[j * 13 + kk] * INV_LN2);

  float e0 = logits[(lbase + t0) * Lc + kk] * INV_LN2;
  int   m0 = mask[lbase + t0];
  float P = m0 ? EXP2F(T[gg * 13 + kk] * INV_LN2 + e0) : ((g == k) ? 1.f : 0.f);
  float off = 0.f;

  for (int t = t0 + 1; t < t1; ++t) {
    float e2 = logits[(lbase + t) * Lc + kk] * INV_LN2;
    int   mk = mask[lbase + t];
    float pj[13];
#pragma unroll
    for (int j = 0; j < 13; ++j) pj[j] = __shfl(P, j, 16);
    float s0 = pj[0] * U[0];  s0 = fmaf(pj[4],  U[4],  s0);
    s0 = fmaf(pj[8],  U[8],  s0);  s0 = fmaf(pj[12], U[12], s0);
    float s1 = pj[1] * U[1];  s1 = fmaf(pj[5],  U[5],  s1);  s1 = fmaf(pj[9],  U[9],  s1);
    float s2 = pj[2] * U[2];  s2 = fmaf(pj[6],  U[6],  s2);  s2 = fmaf(pj[10], U[10], s2);
    float s3 = pj[3] * U[3];  s3 = fmaf(pj[7],  U[7],  s3);  s3 = fmaf(pj[11], U[11], s3);
    float s = (s0 + s1) + (s2 + s3);
    float Pn = EXP2F(e2) * s;
    P = mk ? Pn : P;
    if (((t - t0) & 7) == 0) {   // renorm: keep row max in [1,2)
      float mx = P;
#pragma unroll
      for (int o = 1; o < 16; o <<= 1) mx = fmaxf(mx, __shfl_xor(mx, o, 16));
      unsigned eb = (__float_as_uint(mx) >> 23) & 255u;
      float scale = __uint_as_float((254u - eb) << 23);   // 2^(127-eb)
      P *= scale;
      off += (float)((int)eb - 127);
    }
  }
  if (active) Mout[(size_t)bp * 169 + g * 13 + k] = (P > 0.f) ? (LOG2F(P) + off) : -1e30f;

  // ---- numerator partial for this chunk's tokens [t0, t1) ----
  if (tid < 64) {
    float np = 0.f; int cnt = 0;
    for (int t = t0 + tid; t < t1; t += 64) {
      int mk = mask[lbase + t];
      if (mk) {
        int tg = labels[lbase + t];
        int pg = labels[lbase + t - 1];
        np += T[pg * 13 + tg] + logits[(lbase + t) * Lc + tg];
        cnt += 1;
      }
    }
#pragma unroll
    for (int o = 1; o < 64; o <<= 1) {
      np  += __shfl_xor(np, o, 64);
      cnt += __shfl_xor(cnt, o, 64);
    }
    if (tid == 0) { numpart[bp] = np; cntpart[bp] = (float)cnt; }
  }
}

// ---------------------------------------------------------------------------
// Kernel C: per batch: combine 16 chunk matrices (log2 domain) -> denominator;
// assemble numerator from partials; atomicAdd loss.
// ---------------------------------------------------------------------------
__global__ void k_final(const float* __restrict__ logits, const int* __restrict__ mask,
                        const int* __restrict__ labels, const float* __restrict__ startT,
                        const float* __restrict__ endT, const float* __restrict__ Mws,
                        const float* __restrict__ numpart, const float* __restrict__ cntpart,
                        float* __restrict__ out0) {
  const int b = blockIdx.x;
  const int lane = threadIdx.x;
  const int kk = (lane < 13) ? lane : 0;
  const size_t lbase = (size_t)b * Sc;

  // ---- denominator (log2 domain) ----
  float v = (startT[kk] + logits[lbase * Lc + kk]) * INV_LN2;
  for (int p = 0; p < NCHUNK; ++p) {
    const float* Mp = Mws + (size_t)(b * NCHUNK + p) * 169;
    float a[13];
#pragma unroll
    for (int j = 0; j < 13; ++j) a[j] = __shfl(v, j, 64) + Mp[j * 13 + kk];
    float mx = a[0];
#pragma unroll
    for (int j = 1; j < 13; ++j) mx = fmaxf(mx, a[j]);
    float s = 0.f;
#pragma unroll
    for (int j = 0; j < 13; ++j) s += EXP2F(a[j] - mx);
    v = mx + LOG2F(s);
  }
  float x = (lane < 13) ? (v + endT[kk] * INV_LN2) : -1e30f;
  float mx = x;
#pragma unroll
  for (int off = 1; off < 16; off <<= 1) mx = fmaxf(mx, __shfl_xor(mx, off, 16));
  float sx = EXP2F(x - mx);
#pragma unroll
  for (int off = 1; off < 16; off <<= 1) sx += __shfl_xor(sx, off, 16);
  float den = (mx + LOG2F(sx)) * LN2f;   // valid on lanes 0..15

  // ---- numerator from chunk partials (lanes 0..15) ----
  float np = 0.f, cs = 0.f;
  if (lane < NCHUNK) { np = numpart[b * NCHUNK + lane]; cs = cntpart[b * NCHUNK + lane]; }
#pragma unroll
  for (int o = 1; o < 16; o <<= 1) {
    np += __shfl_xor(np, o, 16);
    cs += __shfl_xor(cs, o, 16);
  }
  if (lane == 0) {
    int lab0 = labels[lbase];
    int seqlen = mask[lbase] + (int)(cs + 0.5f);
    int lastTag = labels[lbase + seqlen - 1];
    float num = startT[lab0] + logits[lbase * Lc + lab0] + np + endT[lastTag];
    float llh = num - den;
    atomicAdd(out0, -llh * (1.0f / Bc));
  }
}

extern "C" void kernel_launch(void* const* d_in, const int* in_sizes, int n_in,
                              void* d_out, int out_size, void* d_ws, size_t ws_size,
                              hipStream_t stream) {
  const float* hs     = (const float*)d_in[0];
  const int*   amask  = (const int*)d_in[1];
  const int*   labels = (const int*)d_in[2];
  const float* W      = (const float*)d_in[3];
  const float* bias   = (const float*)d_in[4];
  const float* startT = (const float*)d_in[5];
  const float* endT   = (const float*)d_in[6];
  const float* T      = (const float*)d_in[7];

  float* out    = (float*)d_out;
  float* logits = out + 1;            // output 1 follows the scalar loss
  float* Mws    = (float*)d_ws;       // 512*169 floats = 346 KB
  float* numpart = Mws + (size_t)NBLK * 169;
  float* cntpart = numpart + NBLK;    // total ~350 KB of ws

  k_logits<<<BSc / ROWS, THREADS, 0, stream>>>(hs, W, bias, logits);
  k_chunks<<<NBLK, 256, 0, stream>>>(logits, amask, labels, T, Mws, numpart, cntpart, out);
  k_final <<<Bc, 64, 0, stream>>>(logits, amask, labels, startT, endT, Mws, numpart, cntpart, out);
}